// Round 1
// baseline (234.915 us; speedup 1.0000x reference)
//
#include <hip/hip_runtime.h>

#define N_PTS   2000000
#define DIM     128
#define KSEL    15
#define TPB     256
#define NBLK1   2048
#define NBLK3   2048
#define CAP     32768
#define FBIG    3.4028235e38f
#define IBIG    0x7fffffff

// ---------------------------------------------------------------------------
// Kernel 1: distances. 16 lanes cooperate on one row (512B, fully coalesced
// as 2x float4 per lane). d2 = sum(t*(t-2x)) + |x|^2, clamped at 0 like ref.
// Also produces per-block min(d2) for the threshold trick.
// ---------------------------------------------------------------------------
__global__ __launch_bounds__(TPB) void k_dist(const float* __restrict__ x,
                                              const float* __restrict__ td,
                                              float* __restrict__ d2out,
                                              float* __restrict__ bmin) {
  const int tid = threadIdx.x;
  const int g   = tid & 15;                          // lane within 16-lane group
  const int grp = blockIdx.x * (TPB / 16) + (tid >> 4);
  const int ngrp = gridDim.x * (TPB / 16);

  const float4* x4 = (const float4*)x;
  float4 xa = x4[g];
  float4 xb = x4[g + 16];
  float xsq = xa.x*xa.x + xa.y*xa.y + xa.z*xa.z + xa.w*xa.w
            + xb.x*xb.x + xb.y*xb.y + xb.z*xb.z + xb.w*xb.w;
#pragma unroll
  for (int m = 1; m < 16; m <<= 1) xsq += __shfl_xor(xsq, m);

  const float4 x2a = make_float4(2.f*xa.x, 2.f*xa.y, 2.f*xa.z, 2.f*xa.w);
  const float4 x2b = make_float4(2.f*xb.x, 2.f*xb.y, 2.f*xb.z, 2.f*xb.w);

  float mymin = FBIG;
  for (int row = grp; row < N_PTS; row += ngrp) {
    const float4* rp = (const float4*)(td + (size_t)row * DIM);
    float4 ta = rp[g];
    float4 tb = rp[g + 16];
    float v;
    v  = ta.x * (ta.x - x2a.x);
    v += ta.y * (ta.y - x2a.y);
    v += ta.z * (ta.z - x2a.z);
    v += ta.w * (ta.w - x2a.w);
    v += tb.x * (tb.x - x2b.x);
    v += tb.y * (tb.y - x2b.y);
    v += tb.z * (tb.z - x2b.z);
    v += tb.w * (tb.w - x2b.w);
#pragma unroll
    for (int m = 1; m < 16; m <<= 1) v += __shfl_xor(v, m);  // within-group reduce
    float d2 = fmaxf(v + xsq, 0.f);
    if (g == 0) d2out[row] = d2;
    mymin = fminf(mymin, d2);
  }

  __shared__ float smin[TPB];
  smin[tid] = mymin;
  __syncthreads();
  for (int s = TPB / 2; s > 0; s >>= 1) {
    if (tid < s) smin[tid] = fminf(smin[tid], smin[tid + s]);
    __syncthreads();
  }
  if (tid == 0) bmin[blockIdx.x] = smin[0];
}

// ---------------------------------------------------------------------------
// Kernel 2: T = 15th-smallest block-min (guarantees >=15 points have d2<=T,
// because each block-min is a real point's d2). Also zeroes candidate counter.
// ---------------------------------------------------------------------------
__global__ __launch_bounds__(TPB) void k_thresh(const float* __restrict__ bmin,
                                                float* __restrict__ thr,
                                                int* __restrict__ cnt) {
  __shared__ float vals[NBLK1];
  __shared__ float s_bv[TPB / 64];
  __shared__ int   s_bi[TPB / 64];
  const int tid = threadIdx.x;
  for (int i = tid; i < NBLK1; i += TPB) vals[i] = bmin[i];
  __syncthreads();

  for (int k = 0; k < KSEL; k++) {
    float bv = FBIG; int bi = IBIG;
    for (int i = tid; i < NBLK1; i += TPB) {
      float v = vals[i];
      if (v < bv) { bv = v; bi = i; }
    }
#pragma unroll
    for (int m = 1; m < 64; m <<= 1) {
      float ov = __shfl_xor(bv, m);
      int   oi = __shfl_xor(bi, m);
      if (ov < bv || (ov == bv && oi < bi)) { bv = ov; bi = oi; }
    }
    if ((tid & 63) == 0) { s_bv[tid >> 6] = bv; s_bi[tid >> 6] = bi; }
    __syncthreads();
    if (tid == 0) {
      float fv = s_bv[0]; int fi = s_bi[0];
      for (int w = 1; w < TPB / 64; w++)
        if (s_bv[w] < fv || (s_bv[w] == fv && s_bi[w] < fi)) { fv = s_bv[w]; fi = s_bi[w]; }
      if (fi >= 0 && fi < NBLK1) vals[fi] = FBIG;   // extract
      if (k == KSEL - 1) thr[0] = fv;
    }
    __syncthreads();
  }
  if (tid == 0) cnt[0] = 0;
}

// ---------------------------------------------------------------------------
// Kernel 3: compact indices with d2 <= T.
// ---------------------------------------------------------------------------
__global__ __launch_bounds__(TPB) void k_compact(const float* __restrict__ d2,
                                                 const float* __restrict__ thr,
                                                 int* __restrict__ cnt,
                                                 int* __restrict__ cand) {
  const float T = thr[0];
  int i = blockIdx.x * TPB + threadIdx.x;
  const int stride = gridDim.x * TPB;
  for (; i < N_PTS; i += stride) {
    if (d2[i] <= T) {
      int p = atomicAdd(cnt, 1);
      if (p < CAP) cand[p] = i;
    }
  }
}

// ---------------------------------------------------------------------------
// Kernel 4: exact top-15 over candidates, ordered by (d2, index) — lowest
// index wins ties, matching lax.top_k stability. Then vote + argmax
// (strict >, so ties go to the smallest class, matching jnp.argmax).
// One wave; order of candidates in `cand` is irrelevant to the result.
// ---------------------------------------------------------------------------
__global__ __launch_bounds__(64) void k_final(const float* __restrict__ d2,
                                              const int* __restrict__ cnt,
                                              const int* __restrict__ cand,
                                              const int* __restrict__ labels,
                                              float* __restrict__ out) {
  const int lane = threadIdx.x;
  int n = cnt[0];
  if (n > CAP) n = CAP;

  float lv[KSEL]; int li[KSEL];
#pragma unroll
  for (int k = 0; k < KSEL; k++) { lv[k] = FBIG; li[k] = IBIG; }

  for (int c = lane; c < n; c += 64) {
    int idx = cand[c];
    float v = d2[idx];
    if (v < lv[KSEL - 1] || (v == lv[KSEL - 1] && idx < li[KSEL - 1])) {
      int p = KSEL - 1;
      while (p > 0 && (lv[p - 1] > v || (lv[p - 1] == v && li[p - 1] > idx))) {
        lv[p] = lv[p - 1]; li[p] = li[p - 1]; p--;
      }
      lv[p] = v; li[p] = idx;
    }
  }

  // 15-round wave-wide multiway merge of the per-lane sorted lists
  int ptr = 0;
  int c0 = 0, c1 = 0, c2 = 0;
  for (int k = 0; k < KSEL; k++) {
    float hv = (ptr < KSEL) ? lv[ptr] : FBIG;
    int   hi = (ptr < KSEL) ? li[ptr] : IBIG;
    float bv = hv; int bi = hi; int bl = lane;
#pragma unroll
    for (int m = 1; m < 64; m <<= 1) {
      float ov = __shfl_xor(bv, m);
      int   oi = __shfl_xor(bi, m);
      int   ol = __shfl_xor(bl, m);
      if (ov < bv || (ov == bv && oi < bi)) { bv = ov; bi = oi; bl = ol; }
    }
    if (lane == bl) ptr++;
    if (lane == 0 && bi >= 0 && bi < N_PTS) {
      int lb = labels[bi];
      if (lb == 0) c0++; else if (lb == 1) c1++; else c2++;
    }
  }
  if (lane == 0) {
    int best = 0, bc = c0;
    if (c1 > bc) { best = 1; bc = c1; }
    if (c2 > bc) { best = 2; }
    out[0] = (float)best;
  }
}

extern "C" void kernel_launch(void* const* d_in, const int* in_sizes, int n_in,
                              void* d_out, int out_size, void* d_ws, size_t ws_size,
                              hipStream_t stream) {
  const float* x      = (const float*)d_in[0];
  const float* td     = (const float*)d_in[1];
  const int*   labels = (const int*)d_in[2];
  float*       out    = (float*)d_out;

  char* w = (char*)d_ws;
  float* d2   = (float*)w;                                   // N_PTS floats
  float* bmin = (float*)(w + (size_t)N_PTS * sizeof(float)); // NBLK1 floats
  float* thr  = bmin + NBLK1;                                // 1 float
  int*   cnt  = (int*)(thr + 1);                             // 1 int
  int*   cand = cnt + 1;                                     // CAP ints

  k_dist   <<<NBLK1, TPB, 0, stream>>>(x, td, d2, bmin);
  k_thresh <<<1,     TPB, 0, stream>>>(bmin, thr, cnt);
  k_compact<<<NBLK3, TPB, 0, stream>>>(d2, thr, cnt, cand);
  k_final  <<<1,     64,  0, stream>>>(d2, cnt, cand, labels, out);
}